// Round 17
// baseline (118.177 us; speedup 1.0000x reference)
//
#include <hip/hip_runtime.h>
#include <hip/hip_bf16.h>
#include <hip/hip_cooperative_groups.h>
#include <cstddef>

namespace cg = cooperative_groups;

// ---------------------------------------------------------------------------
// ROUND 17: single cooperative kernel = cvt | grid.sync | gemm | grid.sync |
// stage3. r16 probe: gemm ~11 us incl gap; 4-launch overhead ~15-20 us was
// the dominant term -> collapse to ONE launch.
// Math identical to r15:
//   Ev[k][h] = exp2(CEXP*(v.Wv+bv)) bf16 ; Eq[row][h] = exp2(CEXP*(q.Wq+bq)) bf16
//   logit[row][k] = sum_h (-2*wl[h]) * rcp(Ev*Eq + 1) ; masked softmax over k
// ---------------------------------------------------------------------------

typedef __attribute__((ext_vector_type(2))) float          f32x2;
typedef __attribute__((ext_vector_type(4))) float          f32x4;
typedef __attribute__((ext_vector_type(8))) short          bfrag;   // 8 bf16
typedef __attribute__((ext_vector_type(2))) unsigned int   u32x2;
typedef __attribute__((ext_vector_type(4))) unsigned short u16x4;

#define SBAR   __builtin_amdgcn_s_barrier()
#define SCHED0 __builtin_amdgcn_sched_barrier(0)

__device__ __forceinline__ void gload16(const void* g, void* l) {
  __builtin_amdgcn_global_load_lds((const __attribute__((address_space(1))) void*)g,
                                   (__attribute__((address_space(3))) void*)l, 16, 0, 0);
}

__device__ __forceinline__ unsigned int cvtpk(float a, float b) {
  unsigned int r;
  asm("v_cvt_pk_bf16_f32 %0, %1, %2" : "=v"(r) : "v"(a), "v"(b));
  return r;   // low16 = bf16(a), high16 = bf16(b)
}

__device__ __forceinline__ float bf2f(unsigned short u) {
  return __uint_as_float((unsigned int)u << 16);
}

template<int CTRL>
__device__ __forceinline__ float dpp_add(float x) {
  int r = __builtin_amdgcn_update_dpp(0, __float_as_int(x), CTRL, 0xF, 0xF, false);
  return x + __int_as_float(r);
}

// ---------------------------------------------------------------------------
// GEMM tile (r15 structure, device function): tile 64x64, BK=64, one
// 256-thread sub-block (4 waves, 2x2, wave tile 32x32). global_load_lds
// width-16, double-buffered LDS, counted vmcnt(4). Pre-swizzled per-lane
// source chunk p^(row&7); frag reads byte ^((row&7)<<4).
// Unit decode: m = u>>3 (0..76), nt = u&7. v-path m<13 (u<104).
// NOTE: both sub-blocks of a block always run tiles with the SAME Kd
// (v-tiles occupy u 0..103 = blocks 0..51 exactly) -> __syncthreads aligned.
// ---------------------------------------------------------------------------
__device__ __forceinline__ void gemm_tile(
    int u, int t, unsigned short* AsBase, unsigned short* BsBase,
    const unsigned short* __restrict__ vb, const unsigned short* __restrict__ qb,
    const unsigned short* __restrict__ wvb, const unsigned short* __restrict__ wqb,
    const float* __restrict__ bv, const float* __restrict__ bq,
    unsigned short* __restrict__ evw, unsigned short* __restrict__ qpw) {
  const int m  = u >> 3;
  const int nt = u & 7;

  const unsigned short* A; const unsigned short* W; const float* bias;
  int M, Kd, m0;
  const bool vpath = (m < 13);
  if (vpath) { A = vb; W = wvb; bias = bv; M = 800;  Kd = 1024; m0 = m * 64; }
  else       { A = qb; W = wqb; bias = bq; M = 4096; Kd = 768;  m0 = (m - 13) * 64; }
  const int n0 = nt * 64;

  const int lane = t & 63;
  const int wave = t >> 6;
  const int wm   = wave >> 1;
  const int wn   = wave & 1;
  const int la   = lane & 15;
  const int lb   = lane >> 4;

  const int row1 = t >> 3;                   // 0..31
  const int p1   = (t & 7) ^ (row1 & 7);     // pre-swizzled source chunk
  int grA1 = m0 + row1;      if (grA1 >= M) grA1 = M - 1;   // clamp; stores guarded
  int grA2 = m0 + row1 + 32; if (grA2 >= M) grA2 = M - 1;
  const unsigned short* srcA1 = A + (size_t)grA1 * Kd + p1 * 8;
  const unsigned short* srcA2 = A + (size_t)grA2 * Kd + p1 * 8;
  const unsigned short* srcB1 = W + (size_t)(n0 + row1) * Kd + p1 * 8;
  const unsigned short* srcB2 = W + (size_t)(n0 + row1 + 32) * Kd + p1 * 8;

  const int d1 = wave * 512;
  const int d2 = 2048 + wave * 512;

  auto STAGE = [&](int buf, int s) {
    const int o = s * 64;
    gload16(srcA1 + o, AsBase + buf * 4096 + d1);
    gload16(srcA2 + o, AsBase + buf * 4096 + d2);
    gload16(srcB1 + o, BsBase + buf * 4096 + d1);
    gload16(srcB2 + o, BsBase + buf * 4096 + d2);
  };

  f32x4 acc[2][2] = {};

  auto compute = [&](const unsigned short* sa, const unsigned short* sb) {
    bfrag af[2][2], bf[2][2];
#pragma unroll
    for (int r = 0; r < 2; ++r)
#pragma unroll
      for (int kk = 0; kk < 2; ++kk) {
        int rowa = wm * 32 + r * 16 + la;
        af[r][kk] = *(const bfrag*)((const char*)sa +
                     ((rowa * 128 + kk * 64 + lb * 16) ^ ((rowa & 7) << 4)));
        int rowb = wn * 32 + r * 16 + la;
        bf[r][kk] = *(const bfrag*)((const char*)sb +
                     ((rowb * 128 + kk * 64 + lb * 16) ^ ((rowb & 7) << 4)));
      }
#pragma unroll
    for (int kk = 0; kk < 2; ++kk)
#pragma unroll
      for (int r = 0; r < 2; ++r)
#pragma unroll
        for (int c = 0; c < 2; ++c)
          acc[r][c] = __builtin_amdgcn_mfma_f32_16x16x32_bf16(af[r][kk], bf[c][kk], acc[r][c], 0, 0, 0);
  };

  const int nsteps = Kd >> 6;   // 16 (v) / 12 (q)
  STAGE(0, 0);
  STAGE(1, 1);
  for (int s = 0; s < nsteps; ++s) {
    if (s + 1 < nsteps) { asm volatile("s_waitcnt vmcnt(4)" ::: "memory"); }
    else                { asm volatile("s_waitcnt vmcnt(0)" ::: "memory"); }
    SCHED0;
    SBAR; SCHED0;
    compute(AsBase + (s & 1) * 4096, BsBase + (s & 1) * 4096);
    SBAR; SCHED0;
    if (s + 2 < nsteps) STAGE(s & 1, s + 2);
  }

  const float CEXP = 2.885390081777927f;   // 2*log2(e)
  unsigned short* C = vpath ? evw : qpw;
#pragma unroll
  for (int c = 0; c < 2; ++c) {
    int col = n0 + wn * 32 + c * 16 + la;
    float bcol = bias[col];
#pragma unroll
    for (int r = 0; r < 2; ++r) {
      int mbase = m0 + wm * 32 + r * 16 + lb * 4;
#pragma unroll
      for (int e = 0; e < 4; ++e) {
        int mr = mbase + e;
        if (mr < M) {
          float val = __builtin_amdgcn_exp2f((acc[r][c][e] + bcol) * CEXP);
          C[(size_t)mr * 512 + col] = (unsigned short)cvtpk(val, val);
        }
      }
    }
  }
}

// ---------------------------------------------------------------------------
// Mega kernel: 256 blocks x 512 threads (co-resident; cooperative launch).
// LDS arena 67,584 B: gemm uses 2 sub-regions of 32 KB; stage3 overlays
// vpS[50][512] bf16 (51,200) + redS[8][64][8] f32 (16,384).
// waves_per_eu(2,2): 2 waves/SIMD -> 256-VGPR budget, no spill squeeze.
// ---------------------------------------------------------------------------
__global__ void
__attribute__((amdgpu_flat_work_group_size(512, 512), amdgpu_waves_per_eu(2, 2)))
mega(const float* __restrict__ v,  const float* __restrict__ q,
     const int* __restrict__ box_mask,
     const float* __restrict__ Wv, const float* __restrict__ bv,
     const float* __restrict__ Wq, const float* __restrict__ bq,
     const float* __restrict__ Wl, float* __restrict__ out,
     unsigned short* qpw, unsigned short* evw,
     unsigned short* vbuf, unsigned short* qbuf,
     unsigned short* wvb, unsigned short* wqb) {
  cg::grid_group grid = cg::this_grid();
  __attribute__((aligned(16))) __shared__ char smem[67584];

  const int bid = blockIdx.x;
  const int t   = threadIdx.x;

  // ---------- Phase A: fp32 -> bf16 cvt (grid-stride) ----------
  {
    const int total = 1220608;   // f32x4 units: v 204800 | Wv 131072 | q 786432 | Wq 98304
    for (int f = bid * 512 + t; f < total; f += 131072) {
      const float* src; unsigned short* dst; int off;
      if (f < 204800)       { src = v;  dst = vbuf; off = f; }
      else if (f < 335872)  { src = Wv; dst = wvb;  off = f - 204800; }
      else if (f < 1122304) { src = q;  dst = qbuf; off = f - 335872; }
      else                  { src = Wq; dst = wqb;  off = f - 1122304; }
      f32x4 x = ((const f32x4*)src)[off];
      u32x2 p; p[0] = cvtpk(x[0], x[1]); p[1] = cvtpk(x[2], x[3]);
      ((u32x2*)dst)[off] = p;
    }
  }
  grid.sync();

  // ---------- Phase B: fused GEMM (616 tiles, 2 sub-blocks/block) ----------
  {
    const int sub  = t >> 8;          // 0..1
    const int tsub = t & 255;
    unsigned short* As = (unsigned short*)(smem + sub * 32768);
    unsigned short* Bs = As + 8192;   // 16 KB past As

    // round 0: units 0..511 (blocks 0..51 -> v+v, Kd uniform per block)
    gemm_tile(bid * 2 + sub, tsub, As, Bs, vbuf, qbuf, wvb, wqb, bv, bq, evw, qpw);
    // round 1: units 512..615 -> blocks 52..103 (all q-path)
    if (bid >= 52 && bid < 104)
      gemm_tile(512 + (bid - 52) * 2 + sub, tsub, As, Bs, vbuf, qbuf, wvb, wqb, bv, bq, evw, qpw);
  }
  grid.sync();

  // ---------- Phase C: logits + masked softmax (r15 stage3) ----------
  {
    unsigned short (*vpS)[512] = (unsigned short(*)[512])smem;          // 51,200 B
    float (*redS)[64][8]       = (float(*)[64][8])(smem + 51200);       // 16,384 B

    const int b    = bid >> 4;            // batch 0..15
    const int grp  = bid & 15;            // row-group 0..15
    const int wv   = t >> 6;              // wave 0..7
    const int lane = t & 63;
    const int row0 = b * 256 + grp * 16 + wv * 2;

    const unsigned short* q0 = qpw + (size_t)row0 * 512;
    float eq0[8], eq1[8], wlr[8];
#pragma unroll
    for (int j = 0; j < 2; ++j) {
      u16x4 a = *(const u16x4*)&q0[j * 256 + 4 * lane];
      u16x4 c = *(const u16x4*)&q0[512 + j * 256 + 4 * lane];
      f32x4 w = *(const f32x4*)&Wl[j * 256 + 4 * lane];
#pragma unroll
      for (int e = 0; e < 4; ++e) {
        eq0[j * 4 + e] = bf2f(a[e]);
        eq1[j * 4 + e] = bf2f(c[e]);
        wlr[j * 4 + e] = -2.f * w[e];
      }
    }

    // stage Ev[b] (bf16): per-lane source (+lane*8 shorts), uniform dest
    {
      const unsigned short* src = evw + (size_t)b * 25600 + lane * 8;
#pragma unroll
      for (int i = 0; i < 7; ++i) {
        int kr = i * 8 + wv;
        if (kr < 50) gload16(src + kr * 512, &vpS[kr][0]);
      }
    }
    __syncthreads();

    const int g  = lane >> 4;
    const int li = lane & 15;

#pragma unroll 1
    for (int kc = 0; kc < 5; ++kc) {
      float a0[10], a1[10];
#pragma unroll
      for (int i = 0; i < 10; ++i) { a0[i] = 0.f; a1[i] = 0.f; }

#pragma unroll
      for (int i = 0; i < 10; ++i) {
        const unsigned short* vr = &vpS[kc * 10 + i][0];
        u16x4 va  = *(const u16x4*)&vr[4 * lane];
        u16x4 vb2 = *(const u16x4*)&vr[256 + 4 * lane];
#pragma unroll
        for (int e = 0; e < 4; ++e) {
          float evf = bf2f(va[e]);
          a0[i] = fmaf(wlr[e], __builtin_amdgcn_rcpf(fmaf(evf, eq0[e], 1.f)), a0[i]);
          a1[i] = fmaf(wlr[e], __builtin_amdgcn_rcpf(fmaf(evf, eq1[e], 1.f)), a1[i]);
        }
#pragma unroll
        for (int e = 0; e < 4; ++e) {
          float evf = bf2f(vb2[e]);
          a0[i] = fmaf(wlr[4 + e], __builtin_amdgcn_rcpf(fmaf(evf, eq0[4 + e], 1.f)), a0[i]);
          a1[i] = fmaf(wlr[4 + e], __builtin_amdgcn_rcpf(fmaf(evf, eq1[4 + e], 1.f)), a1[i]);
        }
      }

#pragma unroll
      for (int i = 0; i < 10; ++i) {
        int k = kc * 10 + i;
        float s0 = a0[i], s1 = a1[i];
        s0 = dpp_add<0x128>(s0); s0 = dpp_add<0x124>(s0);
        s0 = dpp_add<0x122>(s0); s0 = dpp_add<0x121>(s0);
        s1 = dpp_add<0x128>(s1); s1 = dpp_add<0x124>(s1);
        s1 = dpp_add<0x122>(s1); s1 = dpp_add<0x121>(s1);
        if (li == (k & 15)) {
          f32x2 p; p[0] = s0; p[1] = s1;
          *(f32x2*)&redS[wv][k][g * 2] = p;
        }
      }
    }

    const int k = lane;
    f32x4 ra = *(const f32x4*)&redS[wv][k][0];
    f32x4 rb = *(const f32x4*)&redS[wv][k][4];
    float l0 = (ra[0] + ra[2]) + (rb[0] + rb[2]);
    float l1 = (ra[1] + ra[3]) + (rb[1] + rb[3]);

    int   msk = (k < 50) ? box_mask[b * 50 + k] : 0;
    bool  on  = (k < 50 && msk > 0);
    float L0 = on ? l0 : -1e9f;
    float L1 = on ? l1 : -1e9f;

    float m0 = L0, m1 = L1;
#pragma unroll
    for (int off = 32; off; off >>= 1) {
      m0 = fmaxf(m0, __shfl_xor(m0, off));
      m1 = fmaxf(m1, __shfl_xor(m1, off));
    }
    const float LOG2E = 1.4426950408889634f;
    float e0 = (k < 50) ? __builtin_amdgcn_exp2f((L0 - m0) * LOG2E) : 0.f;
    float e1 = (k < 50) ? __builtin_amdgcn_exp2f((L1 - m1) * LOG2E) : 0.f;
    float s0 = e0, s1 = e1;
#pragma unroll
    for (int off = 32; off; off >>= 1) {
      s0 += __shfl_xor(s0, off);
      s1 += __shfl_xor(s1, off);
    }

    if (k < 50) {
      out[(size_t)row0 * 50 + k]       = e0 / s0;
      out[(size_t)(row0 + 1) * 50 + k] = e1 / s1;
    }
  }
}

// ---------------------------------------------------------------------------
// launch — single cooperative kernel
// ---------------------------------------------------------------------------
extern "C" void kernel_launch(void* const* d_in, const int* in_sizes, int n_in,
                              void* d_out, int out_size, void* d_ws, size_t ws_size,
                              hipStream_t stream) {
  const float* v        = (const float*)d_in[0];
  const float* q        = (const float*)d_in[1];
  const int*   box_mask = (const int*)d_in[2];
  // d_in[3] = tags_attention (unused by reference)
  const float* Wv       = (const float*)d_in[4];
  const float* bv       = (const float*)d_in[5];
  const float* Wq       = (const float*)d_in[6];
  const float* bq       = (const float*)d_in[7];
  const float* Wl       = (const float*)d_in[8];
  // d_in[9] = bl (softmax-invariant, and zero)
  float* out = (float*)d_out;

  char* ws = (char*)d_ws;
  unsigned short* qpw  = (unsigned short*)(ws);               // 4,194,304 B (Eq bf16)
  unsigned short* evw  = (unsigned short*)(ws + 4194304);     //   819,200 B (Ev bf16)
  unsigned short* vbuf = (unsigned short*)(ws + 5013504);     // 1,638,400 B
  unsigned short* qbuf = (unsigned short*)(ws + 6651904);     // 6,291,456 B
  unsigned short* wvb  = (unsigned short*)(ws + 12943360);    // 1,048,576 B
  unsigned short* wqb  = (unsigned short*)(ws + 13991936);    //   786,432 B

  void* args[] = {
    (void*)&v, (void*)&q, (void*)&box_mask, (void*)&Wv, (void*)&bv,
    (void*)&Wq, (void*)&bq, (void*)&Wl, (void*)&out,
    (void*)&qpw, (void*)&evw, (void*)&vbuf, (void*)&qbuf, (void*)&wvb, (void*)&wqb
  };
  hipLaunchCooperativeKernel((const void*)mega, dim3(256), dim3(512),
                             args, 0, stream);
}

// Round 19
// 44.587 us; speedup vs baseline: 2.6505x; 2.6505x over previous
//
#include <hip/hip_runtime.h>
#include <hip/hip_bf16.h>
#include <cstddef>

// ---------------------------------------------------------------------------
// ROUND 19 = ROUND 15 (best: 44.77 us) + cvt f32x8 16B-store micro-opt
// (r18 had a stray-identifier compile error; this is the corrected build).
// r17 lesson: grid.sync ~35 us each on 8-XCD -> multi-kernel stream is right;
// ~19 us of total is fixed harness overhead; kernel work ~26 us vs ~22 floor.
// ---------------------------------------------------------------------------
// B=16, N=4, S=64, K=50, VD=1024, QD=768, H=512; ROWS = B*N*S = 4096
//   Ev[k_glob][h] = exp2(CEXP*(v[b,k,:] .Wv[h,:] + bv[h]))   (bf16, row-major)
//   Eq[row][h]    = exp2(CEXP*(q[row,:] .Wq[h,:] + bq[h]))   (bf16, row-major)
//   logit[row][k] = sum_h (-2*wl[h]) * rcp(Ev[k][h]*Eq[row][h] + 1)
//     (tanh(x) = 1 - 2/(e^{2x}+1); exp2 factorized into the projection
//      spaces; k-uniform sum_h wl dropped: softmax-invariant; CEXP=2*log2e)
//   out = masked softmax over k (50 boxes)
// ---------------------------------------------------------------------------

typedef __attribute__((ext_vector_type(2))) float          f32x2;
typedef __attribute__((ext_vector_type(4))) float          f32x4;
typedef __attribute__((ext_vector_type(8))) short          bfrag;   // 8 bf16
typedef __attribute__((ext_vector_type(2))) unsigned int   u32x2;
typedef __attribute__((ext_vector_type(4))) unsigned int   u32x4;
typedef __attribute__((ext_vector_type(4))) unsigned short u16x4;

#define SBAR   __builtin_amdgcn_s_barrier()
#define SCHED0 __builtin_amdgcn_sched_barrier(0)

__device__ __forceinline__ void gload16(const void* g, void* l) {
  __builtin_amdgcn_global_load_lds((const __attribute__((address_space(1))) void*)g,
                                   (__attribute__((address_space(3))) void*)l, 16, 0, 0);
}

__device__ __forceinline__ unsigned int cvtpk(float a, float b) {
  unsigned int r;
  asm("v_cvt_pk_bf16_f32 %0, %1, %2" : "=v"(r) : "v"(a), "v"(b));
  return r;   // low16 = bf16(a), high16 = bf16(b)
}

__device__ __forceinline__ float bf2f(unsigned short u) {
  return __uint_as_float((unsigned int)u << 16);
}

template<int CTRL>
__device__ __forceinline__ float dpp_add(float x) {
  int r = __builtin_amdgcn_update_dpp(0, __float_as_int(x), CTRL, 0xF, 0xF, false);
  return x + __int_as_float(r);
}

// ---------------------------------------------------------------------------
// fp32 -> bf16 conversion of v, Wv, q, Wq. f32x8 granularity: two f32x4
// loads -> one 16B u32x4 store (half the store instructions of r15).
// segments (f32x8 units): v 102400 | Wv 65536 | q 393216 | Wq 49152
// ---------------------------------------------------------------------------
__global__ void __launch_bounds__(256) cvt_all(
    const float* __restrict__ v, const float* __restrict__ wv,
    const float* __restrict__ q, const float* __restrict__ wq,
    unsigned short* __restrict__ vb, unsigned short* __restrict__ wvb,
    unsigned short* __restrict__ qb, unsigned short* __restrict__ wqb) {
  const int total = 610304;   // f32x8 units
  for (int f = blockIdx.x * 256 + threadIdx.x; f < total; f += gridDim.x * 256) {
    const float* src; unsigned short* dst; int off;
    if (f < 102400)       { src = v;  dst = vb;  off = f; }
    else if (f < 167936)  { src = wv; dst = wvb; off = f - 102400; }
    else if (f < 561152)  { src = q;  dst = qb;  off = f - 167936; }
    else                  { src = wq; dst = wqb; off = f - 561152; }
    f32x4 x0 = ((const f32x4*)src)[off * 2];
    f32x4 x1 = ((const f32x4*)src)[off * 2 + 1];
    u32x4 p;
    p[0] = cvtpk(x0[0], x0[1]); p[1] = cvtpk(x0[2], x0[3]);
    p[2] = cvtpk(x1[0], x1[1]); p[3] = cvtpk(x1[2], x1[3]);
    ((u32x4*)dst)[off] = p;
  }
}

// ---------------------------------------------------------------------------
// Fused bf16 GEMM (r13/r15 structure, UNCHANGED): tile 64x64, BK=64, 4 waves
// (2x2), wave tile 32x32. global_load_lds width-16 staging, double-buffered
// LDS, counted vmcnt(4). Pre-swizzled per-lane source chunk p^(row&7); frag
// reads byte ^((row&7)<<4). m-grouped block decode (id%8 == m%8) for XCD L2
// reuse. Epilogue stores bf16 exp2(CEXP*(acc+bias)).
//   m in [0,13)  : v-proj  M=800,  Kd=1024 -> Ev  (bf16 out)
//   m in [13,77) : q-proj  M=4096, Kd=768  -> Eq  (bf16 out)
// ---------------------------------------------------------------------------
__global__ void __launch_bounds__(256) gemm_bf16(
    const unsigned short* __restrict__ vb, const unsigned short* __restrict__ qb,
    const unsigned short* __restrict__ wvb, const unsigned short* __restrict__ wqb,
    const float* __restrict__ bv, const float* __restrict__ bq,
    unsigned short* __restrict__ evw, unsigned short* __restrict__ qpw) {
  __shared__ unsigned short As[2][64 * 64];   // 8 KB per buf
  __shared__ unsigned short Bs[2][64 * 64];

  const int id = blockIdx.x;
  const int m  = (id & 7) + ((id >> 6) << 3);   // m-tile index
  const int nt = (id >> 3) & 7;                 // n-tile index
  if (m >= 77) return;

  const int t = threadIdx.x;

  const unsigned short* A; const unsigned short* W; const float* bias;
  int M, Kd, m0;
  const bool vpath = (m < 13);
  if (vpath) { A = vb; W = wvb; bias = bv; M = 800;  Kd = 1024; m0 = m * 64; }
  else       { A = qb; W = wqb; bias = bq; M = 4096; Kd = 768;  m0 = (m - 13) * 64; }
  const int n0 = nt * 64;

  const int lane = t & 63;
  const int wave = t >> 6;
  const int wm   = wave >> 1;
  const int wn   = wave & 1;
  const int la   = lane & 15;
  const int lb   = lane >> 4;

  const int row1 = t >> 3;                   // 0..31  (chunk t)
  const int p1   = (t & 7) ^ (row1 & 7);     // pre-swizzled source chunk
  int grA1 = m0 + row1;      if (grA1 >= M) grA1 = M - 1;   // clamp; stores guarded
  int grA2 = m0 + row1 + 32; if (grA2 >= M) grA2 = M - 1;
  const unsigned short* srcA1 = A + (size_t)grA1 * Kd + p1 * 8;
  const unsigned short* srcA2 = A + (size_t)grA2 * Kd + p1 * 8;
  const unsigned short* srcB1 = W + (size_t)(n0 + row1) * Kd + p1 * 8;
  const unsigned short* srcB2 = W + (size_t)(n0 + row1 + 32) * Kd + p1 * 8;

  const int d1 = wave * 512;
  const int d2 = 2048 + wave * 512;

  auto STAGE = [&](int buf, int s) {
    const int o = s * 64;
    gload16(srcA1 + o, &As[buf][d1]);
    gload16(srcA2 + o, &As[buf][d2]);
    gload16(srcB1 + o, &Bs[buf][d1]);
    gload16(srcB2 + o, &Bs[buf][d2]);
  };

  f32x4 acc[2][2] = {};

  auto compute = [&](const unsigned short* sa, const unsigned short* sb) {
    bfrag af[2][2], bf[2][2];
#pragma unroll
    for (int r = 0; r < 2; ++r)
#pragma unroll
      for (int kk = 0; kk < 2; ++kk) {
        int rowa = wm * 32 + r * 16 + la;
        af[r][kk] = *(const bfrag*)((const char*)sa +
                     ((rowa * 128 + kk * 64 + lb * 16) ^ ((rowa & 7) << 4)));
        int rowb = wn * 32 + r * 16 + la;
        bf[r][kk] = *(const bfrag*)((const char*)sb +
                     ((rowb * 128 + kk * 64 + lb * 16) ^ ((rowb & 7) << 4)));
      }
#pragma unroll
    for (int kk = 0; kk < 2; ++kk)
#pragma unroll
      for (int r = 0; r < 2; ++r)
#pragma unroll
        for (int c = 0; c < 2; ++c)
          acc[r][c] = __builtin_amdgcn_mfma_f32_16x16x32_bf16(af[r][kk], bf[c][kk], acc[r][c], 0, 0, 0);
  };

  const int nsteps = Kd >> 6;   // 16 (v) / 12 (q)
  STAGE(0, 0);
  STAGE(1, 1);
  for (int s = 0; s < nsteps; ++s) {
    if (s + 1 < nsteps) { asm volatile("s_waitcnt vmcnt(4)" ::: "memory"); }
    else                { asm volatile("s_waitcnt vmcnt(0)" ::: "memory"); }
    SCHED0;
    SBAR; SCHED0;
    compute(As[s & 1], Bs[s & 1]);
    SBAR; SCHED0;
    if (s + 2 < nsteps) STAGE(s & 1, s + 2);
  }

  const float CEXP = 2.885390081777927f;   // 2*log2(e)
  unsigned short* C = vpath ? evw : qpw;
#pragma unroll
  for (int c = 0; c < 2; ++c) {
    int col = n0 + wn * 32 + c * 16 + la;
    float bcol = bias[col];
#pragma unroll
    for (int r = 0; r < 2; ++r) {
      int mbase = m0 + wm * 32 + r * 16 + lb * 4;
#pragma unroll
      for (int e = 0; e < 4; ++e) {
        int mr = mbase + e;
        if (mr < M) {
          float val = __builtin_amdgcn_exp2f((acc[r][c][e] + bcol) * CEXP);
          C[(size_t)mr * 512 + col] = (unsigned short)cvtpk(val, val);
        }
      }
    }
  }
}

// ---------------------------------------------------------------------------
// Stage 3 (r15, UNCHANGED): two rows per wave, bf16 Ev in LDS, bf16 Eq + wl
// in registers, 5x10 accumulator chunks (no spill), DPP reduce, lane=k
// masked softmax. grid (16,16), 512 thr = 8 waves; waves_per_eu(4,4) pins
// the 128-VGPR budget.
// ---------------------------------------------------------------------------
__global__ void
__attribute__((amdgpu_flat_work_group_size(512, 512), amdgpu_waves_per_eu(4, 4)))
stage3_kernel(
    const unsigned short* __restrict__ ev, const unsigned short* __restrict__ qp,
    const float* __restrict__ wl, const int* __restrict__ box_mask,
    float* __restrict__ out) {
  __shared__ unsigned short vpS[50][512];   // 51,200 B (bf16)
  __shared__ float redS[8][64][8];          // 16,384 B  [wave][k][2g + row]

  const int b    = blockIdx.y;
  const int grp  = blockIdx.x;          // 0..15
  const int t    = threadIdx.x;
  const int wv   = t >> 6;              // 0..7
  const int lane = t & 63;
  const int row0 = b * 256 + grp * 16 + wv * 2;

  const unsigned short* q0 = qp + (size_t)row0 * 512;
  float eq0[8], eq1[8], wlr[8];
#pragma unroll
  for (int j = 0; j < 2; ++j) {
    u16x4 a = *(const u16x4*)&q0[j * 256 + 4 * lane];
    u16x4 c = *(const u16x4*)&q0[512 + j * 256 + 4 * lane];
    f32x4 w = *(const f32x4*)&wl[j * 256 + 4 * lane];
#pragma unroll
    for (int e = 0; e < 4; ++e) {
      eq0[j * 4 + e] = bf2f(a[e]);
      eq1[j * 4 + e] = bf2f(c[e]);
      wlr[j * 4 + e] = -2.f * w[e];
    }
  }

  {
    const unsigned short* src = ev + (size_t)b * 25600 + lane * 8;
#pragma unroll
    for (int i = 0; i < 7; ++i) {
      int kr = i * 8 + wv;
      if (kr < 50) gload16(src + kr * 512, &vpS[kr][0]);
    }
  }
  __syncthreads();

  const int g  = lane >> 4;
  const int li = lane & 15;

#pragma unroll 1
  for (int kc = 0; kc < 5; ++kc) {
    float a0[10], a1[10];
#pragma unroll
    for (int i = 0; i < 10; ++i) { a0[i] = 0.f; a1[i] = 0.f; }

#pragma unroll
    for (int i = 0; i < 10; ++i) {
      const unsigned short* vr = &vpS[kc * 10 + i][0];
      u16x4 va  = *(const u16x4*)&vr[4 * lane];
      u16x4 vb2 = *(const u16x4*)&vr[256 + 4 * lane];
#pragma unroll
      for (int e = 0; e < 4; ++e) {
        float evf = bf2f(va[e]);
        a0[i] = fmaf(wlr[e], __builtin_amdgcn_rcpf(fmaf(evf, eq0[e], 1.f)), a0[i]);
        a1[i] = fmaf(wlr[e], __builtin_amdgcn_rcpf(fmaf(evf, eq1[e], 1.f)), a1[i]);
      }
#pragma unroll
      for (int e = 0; e < 4; ++e) {
        float evf = bf2f(vb2[e]);
        a0[i] = fmaf(wlr[4 + e], __builtin_amdgcn_rcpf(fmaf(evf, eq0[4 + e], 1.f)), a0[i]);
        a1[i] = fmaf(wlr[4 + e], __builtin_amdgcn_rcpf(fmaf(evf, eq1[4 + e], 1.f)), a1[i]);
      }
    }

#pragma unroll
    for (int i = 0; i < 10; ++i) {
      int k = kc * 10 + i;
      float s0 = a0[i], s1 = a1[i];
      s0 = dpp_add<0x128>(s0); s0 = dpp_add<0x124>(s0);
      s0 = dpp_add<0x122>(s0); s0 = dpp_add<0x121>(s0);
      s1 = dpp_add<0x128>(s1); s1 = dpp_add<0x124>(s1);
      s1 = dpp_add<0x122>(s1); s1 = dpp_add<0x121>(s1);
      if (li == (k & 15)) {
        f32x2 p; p[0] = s0; p[1] = s1;
        *(f32x2*)&redS[wv][k][g * 2] = p;
      }
    }
  }

  const int k = lane;
  f32x4 ra = *(const f32x4*)&redS[wv][k][0];
  f32x4 rb = *(const f32x4*)&redS[wv][k][4];
  float l0 = (ra[0] + ra[2]) + (rb[0] + rb[2]);
  float l1 = (ra[1] + ra[3]) + (rb[1] + rb[3]);

  int   msk = (k < 50) ? box_mask[b * 50 + k] : 0;
  bool  on  = (k < 50 && msk > 0);
  float L0 = on ? l0 : -1e9f;
  float L1 = on ? l1 : -1e9f;

  float m0 = L0, m1 = L1;
#pragma unroll
  for (int off = 32; off; off >>= 1) {
    m0 = fmaxf(m0, __shfl_xor(m0, off));
    m1 = fmaxf(m1, __shfl_xor(m1, off));
  }
  const float LOG2E = 1.4426950408889634f;
  float e0 = (k < 50) ? __builtin_amdgcn_exp2f((L0 - m0) * LOG2E) : 0.f;
  float e1 = (k < 50) ? __builtin_amdgcn_exp2f((L1 - m1) * LOG2E) : 0.f;
  float s0 = e0, s1 = e1;
#pragma unroll
  for (int off = 32; off; off >>= 1) {
    s0 += __shfl_xor(s0, off);
    s1 += __shfl_xor(s1, off);
  }

  if (k < 50) {
    out[(size_t)row0 * 50 + k]       = e0 / s0;
    out[(size_t)(row0 + 1) * 50 + k] = e1 / s1;
  }
}

// ---------------------------------------------------------------------------
// launch
// ---------------------------------------------------------------------------
extern "C" void kernel_launch(void* const* d_in, const int* in_sizes, int n_in,
                              void* d_out, int out_size, void* d_ws, size_t ws_size,
                              hipStream_t stream) {
  const float* v        = (const float*)d_in[0];
  const float* q        = (const float*)d_in[1];
  const int*   box_mask = (const int*)d_in[2];
  // d_in[3] = tags_attention (unused by reference)
  const float* Wv       = (const float*)d_in[4];
  const float* bv       = (const float*)d_in[5];
  const float* Wq       = (const float*)d_in[6];
  const float* bq       = (const float*)d_in[7];
  const float* Wl       = (const float*)d_in[8];
  // d_in[9] = bl (softmax-invariant, and zero)
  float* out = (float*)d_out;

  char* ws = (char*)d_ws;
  unsigned short* qpw = (unsigned short*)(ws);               // 4,194,304 B (Eq bf16)
  unsigned short* evw = (unsigned short*)(ws + 4194304);     //   819,200 B (Ev bf16)
  unsigned short* vb  = (unsigned short*)(ws + 5013504);     // 1,638,400 B
  unsigned short* qb  = (unsigned short*)(ws + 6651904);     // 6,291,456 B
  unsigned short* wvb = (unsigned short*)(ws + 12943360);    // 1,048,576 B
  unsigned short* wqb = (unsigned short*)(ws + 13991936);    //   786,432 B

  cvt_all<<<2048, 256, 0, stream>>>(v, Wv, q, Wq, vb, wvb, qb, wqb);
  gemm_bf16<<<dim3(640), 256, 0, stream>>>(vb, qb, wvb, wqb, bv, bq, evw, qpw);
  stage3_kernel<<<dim3(16, 16), 512, 0, stream>>>(evw, qpw, Wl, box_mask, out);
}